// Round 12
// baseline (6080.515 us; speedup 1.0000x reference)
//
#include <hip/hip_runtime.h>
#include <hip/hip_bf16.h>

#define B 256
#define T 256
#define M 256
#define P 256
#define TSTEPS 255
#define NT 1024
#define RG 4      // G-resident Wr chunk-pairs (AGPR-pinned)

typedef unsigned int uint;
typedef _Float16 hf2 __attribute__((ext_vector_type(2)));

#define KEEP4A(v) asm volatile("" : "+a"((v).x), "+a"((v).y), "+a"((v).z), "+a"((v).w))
#define KEEP4V(v) asm volatile("" : "+v"((v).x), "+v"((v).y), "+v"((v).z), "+v"((v).w))

__device__ __forceinline__ float fast_tanh(float x) {
    float e = exp2f(x * 2.885390082f);             // e^(2x)
    return 1.f - 2.f * __builtin_amdgcn_rcpf(e + 1.f);
}
__device__ __forceinline__ float fast_sigmoid(float x) {
    float e = exp2f(-x * 1.442695041f);            // e^(-x)
    return __builtin_amdgcn_rcpf(1.f + e);
}

#if defined(__has_builtin)
#if __has_builtin(__builtin_amdgcn_fdot2)
#define HAVE_FDOT2 1
#endif
#endif

__device__ __forceinline__ float dot2(uint a, uint b, float c) {
#ifdef HAVE_FDOT2
    return __builtin_amdgcn_fdot2(__builtin_bit_cast(hf2, a),
                                  __builtin_bit_cast(hf2, b), c, false);
#else
    hf2 x = __builtin_bit_cast(hf2, a), y = __builtin_bit_cast(hf2, b);
    return c + (float)x.x * (float)y.x + (float)x.y * (float)y.y;
#endif
}

__device__ __forceinline__ uint pk16(float a, float b) {
    return __builtin_bit_cast(uint, __builtin_amdgcn_cvt_pkrtz(a, b));
}

__device__ __forceinline__ float rcp1p(float x) {      // 1/(x+1), rcp(inf)=0
    return __builtin_amdgcn_rcpf(x + 1.f);
}

// release-signal / acquire-wait on an LDS counter
__device__ __forceinline__ void fsig(int* f, int lane) {
    __threadfence_block();
    if (lane == 0) atomicAdd(f, 1);
}
__device__ __forceinline__ void fwait(int* f, int tgt) {
    while (*(volatile int*)f < tgt) __builtin_amdgcn_s_sleep(1);
    __threadfence_block();
}

// ---------------- EU = f16(exp(encoder_h @ Wu + bu)) ----------------
__global__ __launch_bounds__(256) void ue_gemm(
    const float* __restrict__ enc, const float* __restrict__ Wu,
    const float* __restrict__ bu, _Float16* __restrict__ Ue16)
{
    __shared__ float At[32][256];
    const int r0 = blockIdx.x * 32;
    const int tid = threadIdx.x;

    #pragma unroll 4
    for (int i = 0; i < 32; ++i)
        At[i][tid] = enc[(size_t)(r0 + i) * 256 + tid];
    __syncthreads();

    float acc[32];
    #pragma unroll
    for (int r = 0; r < 32; ++r) acc[r] = 0.f;

    for (int k = 0; k < 256; k += 4) {
        float w0 = Wu[(size_t)(k + 0) * 256 + tid];
        float w1 = Wu[(size_t)(k + 1) * 256 + tid];
        float w2 = Wu[(size_t)(k + 2) * 256 + tid];
        float w3 = Wu[(size_t)(k + 3) * 256 + tid];
        #pragma unroll
        for (int r = 0; r < 32; ++r) {
            float4 a4 = *(const float4*)&At[r][k];
            acc[r] += a4.x * w0 + a4.y * w1 + a4.z * w2 + a4.w * w3;
        }
    }
    float bub = bu[tid];
    #pragma unroll 4
    for (int r = 0; r < 32; ++r)
        Ue16[(size_t)(r0 + r) * 256 + tid] =
            (_Float16)exp2f(1.442695041f * (acc[r] + bub));   // e^{u}
}

// ---- Wsz[kc*1024+c] = uint4 of f16 pairs of Wr[kc*8+j][c], j=0..7 ----
__global__ __launch_bounds__(256) void wr_cvt(
    const float* __restrict__ Wr, uint4* __restrict__ Wsz)
{
    int i = blockIdx.x * 256 + threadIdx.x;        // 32768
    int kc = i >> 10, c = i & 1023;
    const float* s = Wr + (size_t)kc * 8 * 1024 + c;
    uint4 o;
    o.x = pk16(s[0 * 1024], s[1 * 1024]);
    o.y = pk16(s[2 * 1024], s[3 * 1024]);
    o.z = pk16(s[4 * 1024], s[5 * 1024]);
    o.w = pk16(s[6 * 1024], s[7 * 1024]);
    Wsz[i] = o;
}

// ---- Wwsz[kk*256+m] = uint4 of f16 pairs of Ww[kk*8+j][m], j=0..7 ----
__global__ __launch_bounds__(256) void ww_cvt(
    const float* __restrict__ Ww, uint4* __restrict__ Wwsz)
{
    int i = blockIdx.x * 256 + threadIdx.x;        // 16384
    int kk = i >> 8, m = i & 255;
    const float* s = Ww + (size_t)kk * 8 * 256 + m;
    uint4 o;
    o.x = pk16(s[0 * 256], s[1 * 256]);
    o.y = pk16(s[2 * 256], s[3 * 256]);
    o.z = pk16(s[4 * 256], s[5 * 256]);
    o.w = pk16(s[6 * 256], s[7 * 256]);
    Wwsz[i] = o;
}

// ---------------- main scan: one block (1024 thr) per batch element ----------------
// Flag-synced pipeline; G streams Wr with an explicit 2-deep load pipeline.
__global__ __launch_bounds__(NT, 4) void decoder_scan(
    const float* __restrict__ data,
    const float* __restrict__ h0,  const float* __restrict__ s0,
    const float* __restrict__ Wd,  const float* __restrict__ bd,
    const float* __restrict__ Wk,  const float* __restrict__ bl,
    const float* __restrict__ bw,
    const float* __restrict__ Wv,  const float* __restrict__ bv,
    const float* __restrict__ Wvb, const float* __restrict__ bvb,
    const float* __restrict__ Wwb, const float* __restrict__ bwb,
    const float* __restrict__ enc,
    const _Float16* __restrict__ Ue16g,
    const uint4* __restrict__ Wsz, const uint4* __restrict__ Wwsz,
    float* __restrict__ out)
{
    const int b    = blockIdx.x;
    const int tid  = threadIdx.x;
    const int lane = tid & 63;
    const int wave = tid >> 6;          // 0..15

    __shared__ __align__(16) uint4 ww_lds[2 * 16 * 256];   // 128 KB, wave-linear layout
    __shared__ float h_lds[P], s_lds[P];
    __shared__ __align__(16) uint hs2[128 + 4 + 128];      // h2 @0, s2 @132
    __shared__ float z_lds[4 * 257];
    __shared__ __align__(16) uint  edup[2][132];           // ED f16 pairs, dup copies
    __shared__ __align__(16) float wv2dup[2][264];         // 2*Wv f32, dup copies
    __shared__ float el_lds[T];
    __shared__ float g_lds[T];
    __shared__ float ctx_lds[M];
    __shared__ __align__(16) float sred[8], yred[8];
    __shared__ float ya[4];
    __shared__ float data_lds[TSTEPS + 1];
    __shared__ int pf, zf, ef, df;

    uint* h2_lds = hs2;
    uint* s2_lds = hs2 + 132;

    // ---- stage Ww halves into LDS (wave-linear layout) ----
    {
        #pragma unroll
        for (int k = 0; k < 8; ++k) {
            int l = tid + k * NT;                  // 0..8191
            int i = l >> 9, r = l & 511, dmm = r >> 1, dk = r & 1;
            ww_lds[l] = Wwsz[((dk * 32 + i) << 8) + dmm];
        }
    }
    if (tid == 0) { pf = 0; zf = 0; ef = 0; df = 0; }
    if (tid < 256) {
        float hv = h0[b * 256 + tid], sv = s0[b * 256 + tid];
        h_lds[tid] = hv; s_lds[tid] = sv; ctx_lds[tid] = 0.f;
        float w2 = 2.f * Wv[tid];
        wv2dup[0][tid] = w2; wv2dup[1][tid] = w2;
        float hv1 = __shfl_down(hv, 1, 64);
        float sv1 = __shfl_down(sv, 1, 64);
        if (!(tid & 1)) {
            h2_lds[tid >> 1] = pk16(hv, hv1);
            s2_lds[tid >> 1] = pk16(sv, sv1);
        }
    }
    if (tid < 8) { sred[tid] = 1.f; yred[tid] = 0.f; }   // ctx_0 = 0
    if (tid < TSTEPS) data_lds[tid] = data[b * TSTEPS + tid];

    const float Wd0 = Wd[0], bd0 = bd[0];
    const float* encB = enc + (size_t)b * T * M;

    // ---- g[tp] = <enc[tp,:], Wd[1:]> ----
    {
        float w0 = Wd[1 + lane * 4], w1 = Wd[2 + lane * 4];
        float w2 = Wd[3 + lane * 4], w3 = Wd[4 + lane * 4];
        for (int i = 0; i < 16; ++i) {
            int tp = wave * 16 + i;
            float4 e4 = *(const float4*)&encB[(size_t)tp * 256 + lane * 4];
            float p = e4.x * w0 + e4.y * w1 + e4.z * w2 + e4.w * w3;
            #pragma unroll
            for (int mm = 32; mm >= 1; mm >>= 1) p += __shfl_xor(p, mm, 64);
            if (lane == 0) g_lds[tp] = p;
        }
    }
    __syncthreads();

    const uint4* h2u4 = (const uint4*)h2_lds;
    const uint4* s2u4 = (const uint4*)s2_lds;

    // ---- prologue: acc_0 = Wr·h_0 (all threads, 1 col each) ----
    {
        const uint4* wc = Wsz + tid;
        float acc = 0.f;
        #pragma unroll 4
        for (int kc = 0; kc < 32; ++kc) {
            uint4 w = wc[kc << 10];
            uint4 h = h2u4[kc];
            acc = dot2(w.x, h.x, acc); acc = dot2(w.y, h.y, acc);
            acc = dot2(w.z, h.z, acc); acc = dot2(w.w, h.w, acc);
        }
        z_lds[(tid >> 8) * 257 + (tid & 255)] = acc;
    }
    __syncthreads();

    if (wave < 8) {
        // ================= G-path (512 threads) =================
        const int gate = tid & 3, uu0 = tid >> 2, uu1 = uu0 + 128;
        const int cz0 = gate * 257 + uu0, cz1 = gate * 257 + uu1;
        const float wk0 = Wk[gate * 256 + uu0], bl0 = bl[gate * 256 + uu0];
        const float wk1 = Wk[gate * 256 + uu1], bl1 = bl[gate * 256 + uu1];
        const int zr = tid >> 8, zc = tid & 255;
        const uint4* wcA = Wsz + tid;
        const uint4* wcB = Wsz + tid + 512;
        uint4 rA[RG], rB[RG];
        #pragma unroll
        for (int kc = 0; kc < RG; ++kc) {
            rA[kc] = wcA[kc << 10]; rB[kc] = wcB[kc << 10];
            KEEP4A(rA[kc]); KEEP4A(rB[kc]);
        }

        for (int t = 0; t < TSTEPS; ++t) {
            // group-0 streamed loads issue before any wait (fly during P1)
            uint4 sA[4], sB[4];
            #pragma unroll
            for (int i = 0; i < 4; ++i) {
                sA[i] = wcA[(RG + i) << 10]; sB[i] = wcB[(RG + i) << 10];
            }

            fwait(&zf, 8 * t);                       // z(t) ready
            fwait(&ef, 8 * t);                       // sred/yred from E(t-1)
            // ---- P1: ys; gates for 2 columns; write h,s,h2,s2 ----
            {
                float4 sa = *(const float4*)&sred[0], sb = *(const float4*)&sred[4];
                float4 yaa = *(const float4*)&yred[0], yab = *(const float4*)&yred[4];
                float S = sa.x + sa.y + sa.z + sa.w + sb.x + sb.y + sb.z + sb.w;
                float Y = yaa.x + yaa.y + yaa.z + yaa.w + yab.x + yab.y + yab.z + yab.w;
                float ys = Y * __builtin_amdgcn_rcpf(S) + data_lds[t] * Wd0 + bd0;
                float zc0 = z_lds[cz0] + ys * wk0 + bl0;
                float zc1 = z_lds[cz1] + ys * wk1 + bl1;
                float nl0 = (gate == 2) ? fast_tanh(zc0) : fast_sigmoid(zc0);
                float nl1 = (gate == 2) ? fast_tanh(zc1) : fast_sigmoid(zc1);
                float a1 = __shfl_xor(nl0, 1, 64);
                float a2 = __shfl_xor(nl0, 2, 64);
                float a3 = __shfl_xor(nl0, 3, 64);
                float b1 = __shfl_xor(nl1, 1, 64);
                float b2 = __shfl_xor(nl1, 2, 64);
                float b3 = __shfl_xor(nl1, 3, 64);
                float hn0 = 0.f, sv0 = 0.f, hn1 = 0.f, sv1 = 0.f;
                if (gate == 0) {            // nl=sig_i a1=sig_f a2=tanh_g a3=sig_o
                    sv0 = a1 * s_lds[uu0] + nl0 * a2;
                    hn0 = a3 * fast_tanh(sv0);
                    sv1 = b1 * s_lds[uu1] + nl1 * b2;
                    hn1 = b3 * fast_tanh(sv1);
                    s_lds[uu0] = sv0; h_lds[uu0] = hn0;
                    s_lds[uu1] = sv1; h_lds[uu1] = hn1;
                }
                float hd0 = __shfl_down(hn0, 4, 64), sd0 = __shfl_down(sv0, 4, 64);
                float hd1 = __shfl_down(hn1, 4, 64), sd1 = __shfl_down(sv1, 4, 64);
                if ((tid & 7) == 0) {
                    h2_lds[uu0 >> 1] = pk16(hn0, hd0); s2_lds[uu0 >> 1] = pk16(sv0, sd0);
                    h2_lds[uu1 >> 1] = pk16(hn1, hd1); s2_lds[uu1 >> 1] = pk16(sv1, sd1);
                }
            }
            fsig(&pf, lane);                         // P1 done
            fwait(&pf, 8 * (t + 1));                 // all h2/s2 written

            float a0 = 0.f, a1 = 0.f;
            #pragma unroll
            for (int kc = 0; kc < RG; ++kc) {        // reg-resident
                uint4 h = h2u4[kc];
                a0 = dot2(rA[kc].x, h.x, a0); a0 = dot2(rA[kc].y, h.y, a0);
                a0 = dot2(rA[kc].z, h.z, a0); a0 = dot2(rA[kc].w, h.w, a0);
                a1 = dot2(rB[kc].x, h.x, a1); a1 = dot2(rB[kc].y, h.y, a1);
                a1 = dot2(rB[kc].z, h.z, a1); a1 = dot2(rB[kc].w, h.w, a1);
            }
            // ---- streamed kc RG..31: 7 groups of 4, 2-deep pipeline ----
            #pragma unroll
            for (int g = 0; g < 7; ++g) {
                uint4 nA[4], nB[4];
                if (g < 6) {
                    #pragma unroll
                    for (int i = 0; i < 4; ++i) {
                        nA[i] = wcA[(RG + 4 * (g + 1) + i) << 10];
                        nB[i] = wcB[(RG + 4 * (g + 1) + i) << 10];
                    }
                }
                #pragma unroll
                for (int i = 0; i < 4; ++i) {
                    uint4 h = h2u4[RG + 4 * g + i];
                    a0 = dot2(sA[i].x, h.x, a0); a0 = dot2(sA[i].y, h.y, a0);
                    a0 = dot2(sA[i].z, h.z, a0); a0 = dot2(sA[i].w, h.w, a0);
                    a1 = dot2(sB[i].x, h.x, a1); a1 = dot2(sB[i].y, h.y, a1);
                    a1 = dot2(sB[i].z, h.z, a1); a1 = dot2(sB[i].w, h.w, a1);
                }
                #pragma unroll
                for (int i = 0; i < 4; ++i) { sA[i] = nA[i]; sB[i] = nB[i]; }
            }
            z_lds[zr * 257 + zc] = a0;
            z_lds[(2 + zr) * 257 + zc] = a1;
            fsig(&zf, lane);                         // z(t+1) ready
        }
    } else {
        // ================= A-path (512 threads) =================
        const int aw  = wave - 8;
        const int aid = tid - 512;
        const int dm  = aid >> 1;                   // D: m-col / E: row
        const int dkh = aid & 1;                    // D: K-half, E: m-half
        const float bwm = bw[dm];
        const uint4* wwp  = Wwsz + (dkh << 13) + dm;        // global stream
        const uint4* wwl  = ww_lds + aid;                   // LDS, wave-linear
        const uint4*  edT = (const uint4*)(&edup[dkh][0]) + (dkh << 4);
        const float4* wvT = (const float4*)(&wv2dup[dkh][0]) + (dkh << 5);
        const uint4* cat4 = dkh ? s2u4 : h2u4;

        // ---- EU row-half into registers: 8 chunks AGPR-pinned, 8 arch-pinned ----
        uint4 eu[16];
        {
            const uint4* eusrc = (const uint4*)(Ue16g + (size_t)b * T * M) + (aid << 4);
            #pragma unroll
            for (int i = 0; i < 8; ++i)  { eu[i] = eusrc[i]; KEEP4A(eu[i]); }
            #pragma unroll
            for (int i = 8; i < 16; ++i) { eu[i] = eusrc[i]; KEEP4V(eu[i]); }
        }

        for (int t = 0; t < TSTEPS; ++t) {
            // prefetch first streamed Ww chunks (fly during pf wait)
            uint4 e0 = wwp[16 << 8], e1 = wwp[17 << 8];
            uint4 e2 = wwp[18 << 8], e3 = wwp[19 << 8];
            fwait(&pf, 8 * (t + 1));                 // h2/s2 ready
            // ---- D: 16 LDS chunks + 16 streamed ----
            float a = 0.f;
            #pragma unroll 4
            for (int i = 0; i < 16; ++i) {
                uint4 w = wwl[i << 9];
                uint4 c = cat4[i];
                a = dot2(w.x, c.x, a); a = dot2(w.y, c.y, a);
                a = dot2(w.z, c.z, a); a = dot2(w.w, c.w, a);
            }
            {
                uint4 c = cat4[16];
                a = dot2(e0.x, c.x, a); a = dot2(e0.y, c.y, a);
                a = dot2(e0.z, c.z, a); a = dot2(e0.w, c.w, a);
                c = cat4[17];
                a = dot2(e1.x, c.x, a); a = dot2(e1.y, c.y, a);
                a = dot2(e1.z, c.z, a); a = dot2(e1.w, c.w, a);
                c = cat4[18];
                a = dot2(e2.x, c.x, a); a = dot2(e2.y, c.y, a);
                a = dot2(e2.z, c.z, a); a = dot2(e2.w, c.w, a);
                c = cat4[19];
                a = dot2(e3.x, c.x, a); a = dot2(e3.y, c.y, a);
                a = dot2(e3.z, c.z, a); a = dot2(e3.w, c.w, a);
            }
            #pragma unroll 4
            for (int i = 20; i < 32; ++i) {
                uint4 w = wwp[i << 8];
                uint4 c = cat4[i];
                a = dot2(w.x, c.x, a); a = dot2(w.y, c.y, a);
                a = dot2(w.z, c.z, a); a = dot2(w.w, c.w, a);
            }
            a += __shfl_xor(a, 1, 64);               // merge K-halves
            float ed = exp2f(1.442695041f * (a + bwm));   // e^{dsc}
            float ed2 = __shfl_xor(ed, 2, 64);            // partner m+1
            if ((aid & 3) == 0) {
                uint u = pk16(ed, ed2);
                edup[0][dm >> 1] = u;
                edup[1][dm >> 1] = u;
            }
            fsig(&df, lane);                         // ED written
            fwait(&df, 8 * (t + 1));

            // ---- E: per-element rcp form (plain packed math, EU in regs) ----
            __builtin_amdgcn_s_setprio(1);
            float pl = 0.f;                          // Σ 2wv / (q+1), q=(eu·ed)²
            #pragma unroll
            for (int jj = 0; jj < 16; ++jj) {
                uint4 u = eu[jj];
                uint4 d = edT[jj];
                float4 wA = wvT[jj * 2], wB = wvT[jj * 2 + 1];
                hf2 g0 = __builtin_bit_cast(hf2, u.x) * __builtin_bit_cast(hf2, d.x);
                hf2 g1 = __builtin_bit_cast(hf2, u.y) * __builtin_bit_cast(hf2, d.y);
                hf2 g2 = __builtin_bit_cast(hf2, u.z) * __builtin_bit_cast(hf2, d.z);
                hf2 g3 = __builtin_bit_cast(hf2, u.w) * __builtin_bit_cast(hf2, d.w);
                g0 = g0 * g0; g1 = g1 * g1; g2 = g2 * g2; g3 = g3 * g3;
                pl = fmaf(wA.x, rcp1p((float)g0.x), pl);
                pl = fmaf(wA.y, rcp1p((float)g0.y), pl);
                pl = fmaf(wA.z, rcp1p((float)g1.x), pl);
                pl = fmaf(wA.w, rcp1p((float)g1.y), pl);
                pl = fmaf(wB.x, rcp1p((float)g2.x), pl);
                pl = fmaf(wB.y, rcp1p((float)g2.y), pl);
                pl = fmaf(wB.z, rcp1p((float)g3.x), pl);
                pl = fmaf(wB.w, rcp1p((float)g3.y), pl);
            }
            pl += __shfl_xor(pl, 1, 64);             // merge m-halves
            float ev = exp2f(-1.442695041f * pl);    // softmax const dropped
            if (!dkh) el_lds[dm] = ev;
            float yg = ev * g_lds[dm];
            #pragma unroll
            for (int mm = 2; mm <= 32; mm <<= 1) {
                ev += __shfl_xor(ev, mm, 64);
                yg += __shfl_xor(yg, mm, 64);
            }
            if (lane == 0) { sred[aw] = ev; yred[aw] = yg; }
            __builtin_amdgcn_s_setprio(0);
            fsig(&ef, lane);                         // E(t) done
        }
    }

    __syncthreads();                                 // converge before epilogue

    // ---- epilogue: final ctx from el(254) + fp32 enc, then output head ----
    {
        float S;
        {
            float4 sa = *(const float4*)&sred[0], sb = *(const float4*)&sred[4];
            S = sa.x + sa.y + sa.z + sa.w + sb.x + sb.y + sb.z + sb.w;
        }
        float a0 = 0.f, a1 = 0.f, a2 = 0.f, a3 = 0.f;
        for (int i = 0; i < 16; ++i) {
            int tp = wave * 16 + i;
            float w = el_lds[tp];
            float4 e4 = *(const float4*)&encB[(size_t)tp * 256 + lane * 4];
            a0 += w * e4.x; a1 += w * e4.y; a2 += w * e4.z; a3 += w * e4.w;
        }
        atomicAdd(&ctx_lds[lane * 4 + 0], a0);
        atomicAdd(&ctx_lds[lane * 4 + 1], a1);
        atomicAdd(&ctx_lds[lane * 4 + 2], a2);
        atomicAdd(&ctx_lds[lane * 4 + 3], a3);
        __syncthreads();

        float qp = 0.f;
        if (tid < 256) {
            float ctx = ctx_lds[tid] * __builtin_amdgcn_rcpf(S);
            qp = h_lds[tid] * Wvb[tid] + ctx * Wvb[256 + tid];
        }
        if (wave < 4) {
            #pragma unroll
            for (int mm = 32; mm >= 1; mm >>= 1) qp += __shfl_xor(qp, mm, 64);
            if (lane == 0) ya[wave] = qp;
        }
        __syncthreads();
        if (tid < 256) {
            float qv = ya[0] + ya[1] + ya[2] + ya[3] + bvb[0];
            out[b * 256 + tid] = qv * Wwb[tid] + bwb[tid];
        }
    }
}

extern "C" void kernel_launch(void* const* d_in, const int* in_sizes, int n_in,
                              void* d_out, int out_size, void* d_ws, size_t ws_size,
                              hipStream_t stream) {
    const float* data = (const float*)d_in[0];
    const float* enc  = (const float*)d_in[1];
    const float* h0   = (const float*)d_in[2];
    const float* s0   = (const float*)d_in[3];
    const float* Wd   = (const float*)d_in[4];
    const float* bd   = (const float*)d_in[5];
    const float* Wk   = (const float*)d_in[6];
    const float* Wr   = (const float*)d_in[7];
    const float* bl   = (const float*)d_in[8];
    const float* Ww   = (const float*)d_in[9];
    const float* bw   = (const float*)d_in[10];
    const float* Wu   = (const float*)d_in[11];
    const float* bu   = (const float*)d_in[12];
    const float* Wv   = (const float*)d_in[13];
    const float* bv   = (const float*)d_in[14];
    const float* Wvb  = (const float*)d_in[15];
    const float* bvb  = (const float*)d_in[16];
    const float* Wwb  = (const float*)d_in[17];
    const float* bwb  = (const float*)d_in[18];

    _Float16* Ue16 = (_Float16*)d_ws;                                 // 32 MB
    uint4* Wsz  = (uint4*)((char*)d_ws + (32ull << 20));              // 512 KB
    uint4* Wwsz = (uint4*)((char*)d_ws + (32ull << 20) + (512ull << 10)); // 256 KB
    float* out = (float*)d_out;

    hipLaunchKernelGGL(ue_gemm, dim3((B * T) / 32), dim3(256), 0, stream,
                       enc, Wu, bu, Ue16);
    hipLaunchKernelGGL(wr_cvt, dim3(128), dim3(256), 0, stream, Wr, Wsz);
    hipLaunchKernelGGL(ww_cvt, dim3(64), dim3(256), 0, stream, Ww, Wwsz);
    hipLaunchKernelGGL(decoder_scan, dim3(B), dim3(NT), 0, stream,
                       data, h0, s0, Wd, bd, Wk, bl, bw,
                       Wv, bv, Wvb, bvb, Wwb, bwb,
                       enc, Ue16, Wsz, Wwsz, out);
}

// Round 13
// 2386.681 us; speedup vs baseline: 2.5477x; 2.5477x over previous
//
#include <hip/hip_runtime.h>
#include <hip/hip_bf16.h>

#define B 256
#define T 256
#define M 256
#define P 256
#define TSTEPS 255
#define NT 1024
#define RG 8      // G-resident Wr chunk-pairs (asm-pinned -> AGPR-parked)

typedef unsigned int uint;
typedef _Float16 hf2 __attribute__((ext_vector_type(2)));

#define KEEP4(v) asm volatile("" : "+v"((v).x), "+v"((v).y), "+v"((v).z), "+v"((v).w))

__device__ __forceinline__ float fast_tanh(float x) {
    float e = exp2f(x * 2.885390082f);             // e^(2x)
    return 1.f - 2.f * __builtin_amdgcn_rcpf(e + 1.f);
}
__device__ __forceinline__ float fast_sigmoid(float x) {
    float e = exp2f(-x * 1.442695041f);            // e^(-x)
    return __builtin_amdgcn_rcpf(1.f + e);
}

#if defined(__has_builtin)
#if __has_builtin(__builtin_amdgcn_fdot2)
#define HAVE_FDOT2 1
#endif
#endif

__device__ __forceinline__ float dot2(uint a, uint b, float c) {
#ifdef HAVE_FDOT2
    return __builtin_amdgcn_fdot2(__builtin_bit_cast(hf2, a),
                                  __builtin_bit_cast(hf2, b), c, false);
#else
    hf2 x = __builtin_bit_cast(hf2, a), y = __builtin_bit_cast(hf2, b);
    return c + (float)x.x * (float)y.x + (float)x.y * (float)y.y;
#endif
}

__device__ __forceinline__ uint pk16(float a, float b) {
    return __builtin_bit_cast(uint, __builtin_amdgcn_cvt_pkrtz(a, b));
}

// packed (u*d)^2 in f16x2 — forced v_pk codegen
__device__ __forceinline__ uint pkmulsq(uint a, uint b) {
    uint p;
    asm("v_pk_mul_f16 %0, %1, %2\n\t"
        "v_pk_mul_f16 %0, %0, %0" : "=v"(p) : "v"(a), "v"(b));
    return p;
}

__device__ __forceinline__ float rcp1p(float x) {      // 1/(x+1), rcp(inf)=0
    return __builtin_amdgcn_rcpf(x + 1.f);
}

// ---------------- EU = f16(exp(encoder_h @ Wu + bu)) ----------------
__global__ __launch_bounds__(256) void ue_gemm(
    const float* __restrict__ enc, const float* __restrict__ Wu,
    const float* __restrict__ bu, _Float16* __restrict__ Ue16)
{
    __shared__ float At[32][256];
    const int r0 = blockIdx.x * 32;
    const int tid = threadIdx.x;

    #pragma unroll 4
    for (int i = 0; i < 32; ++i)
        At[i][tid] = enc[(size_t)(r0 + i) * 256 + tid];
    __syncthreads();

    float acc[32];
    #pragma unroll
    for (int r = 0; r < 32; ++r) acc[r] = 0.f;

    for (int k = 0; k < 256; k += 4) {
        float w0 = Wu[(size_t)(k + 0) * 256 + tid];
        float w1 = Wu[(size_t)(k + 1) * 256 + tid];
        float w2 = Wu[(size_t)(k + 2) * 256 + tid];
        float w3 = Wu[(size_t)(k + 3) * 256 + tid];
        #pragma unroll
        for (int r = 0; r < 32; ++r) {
            float4 a4 = *(const float4*)&At[r][k];
            acc[r] += a4.x * w0 + a4.y * w1 + a4.z * w2 + a4.w * w3;
        }
    }
    float bub = bu[tid];
    #pragma unroll 4
    for (int r = 0; r < 32; ++r)
        Ue16[(size_t)(r0 + r) * 256 + tid] =
            (_Float16)exp2f(1.442695041f * (acc[r] + bub));   // e^{u}
}

// ---- Wsz[kc*1024+c] = uint4 of f16 pairs of Wr[kc*8+j][c], j=0..7 ----
__global__ __launch_bounds__(256) void wr_cvt(
    const float* __restrict__ Wr, uint4* __restrict__ Wsz)
{
    int i = blockIdx.x * 256 + threadIdx.x;        // 32768
    int kc = i >> 10, c = i & 1023;
    const float* s = Wr + (size_t)kc * 8 * 1024 + c;
    uint4 o;
    o.x = pk16(s[0 * 1024], s[1 * 1024]);
    o.y = pk16(s[2 * 1024], s[3 * 1024]);
    o.z = pk16(s[4 * 1024], s[5 * 1024]);
    o.w = pk16(s[6 * 1024], s[7 * 1024]);
    Wsz[i] = o;
}

// ---- Wwsz[kk*256+m] = uint4 of f16 pairs of Ww[kk*8+j][m], j=0..7 ----
__global__ __launch_bounds__(256) void ww_cvt(
    const float* __restrict__ Ww, uint4* __restrict__ Wwsz)
{
    int i = blockIdx.x * 256 + threadIdx.x;        // 16384
    int kk = i >> 8, m = i & 255;
    const float* s = Ww + (size_t)kk * 8 * 256 + m;
    uint4 o;
    o.x = pk16(s[0 * 256], s[1 * 256]);
    o.y = pk16(s[2 * 256], s[3 * 256]);
    o.z = pk16(s[4 * 256], s[5 * 256]);
    o.w = pk16(s[6 * 256], s[7 * 256]);
    Wwsz[i] = o;
}

// ---------------- main scan: one block (1024 thr) per batch element ----------------
__global__ __launch_bounds__(NT, 4) void decoder_scan(
    const float* __restrict__ data,
    const float* __restrict__ h0,  const float* __restrict__ s0,
    const float* __restrict__ Wd,  const float* __restrict__ bd,
    const float* __restrict__ Wk,  const float* __restrict__ bl,
    const float* __restrict__ bw,
    const float* __restrict__ Wv,  const float* __restrict__ bv,
    const float* __restrict__ Wvb, const float* __restrict__ bvb,
    const float* __restrict__ Wwb, const float* __restrict__ bwb,
    const float* __restrict__ enc,
    const _Float16* __restrict__ Ue16g,
    const uint4* __restrict__ Wsz, const uint4* __restrict__ Wwsz,
    float* __restrict__ out)
{
    const int b    = blockIdx.x;
    const int tid  = threadIdx.x;
    const int lane = tid & 63;
    const int wave = tid >> 6;          // 0..15

    __shared__ __align__(16) uint4 ww_lds[2 * 16 * 256];   // 128 KB, wave-linear layout
    __shared__ float h_lds[P], s_lds[P];
    __shared__ __align__(16) uint hs2[128 + 4 + 128];      // h2 @0, s2 @132
    __shared__ float z_lds[4 * 257];
    __shared__ __align__(16) uint  edup[2][132];           // ED f16 pairs, dup copies
    __shared__ __align__(16) float wv2dup[2][264];         // 2*Wv f32, dup copies
    __shared__ float el_lds[T];
    __shared__ float g_lds[T];
    __shared__ float ctx_lds[M];
    __shared__ __align__(16) float sred[8], yred[8];
    __shared__ float ya[4];
    __shared__ float data_lds[TSTEPS + 1];
    __shared__ int aflag;

    uint* h2_lds = hs2;
    uint* s2_lds = hs2 + 132;

    // ---- stage Ww halves into LDS: ww_lds[(i<<9)+(dm<<1)+dkh] = Wwsz[((dkh*32+i)<<8)+dm]
    {
        #pragma unroll
        for (int k = 0; k < 8; ++k) {
            int l = tid + k * NT;                  // 0..8191
            int i = l >> 9, r = l & 511, dmm = r >> 1, dk = r & 1;
            ww_lds[l] = Wwsz[((dk * 32 + i) << 8) + dmm];
        }
    }
    if (tid == 0) aflag = 0;
    if (tid < 256) {
        float hv = h0[b * 256 + tid], sv = s0[b * 256 + tid];
        h_lds[tid] = hv; s_lds[tid] = sv; ctx_lds[tid] = 0.f;
        float w2 = 2.f * Wv[tid];
        wv2dup[0][tid] = w2; wv2dup[1][tid] = w2;
        float hv1 = __shfl_down(hv, 1, 64);
        float sv1 = __shfl_down(sv, 1, 64);
        if (!(tid & 1)) {
            h2_lds[tid >> 1] = pk16(hv, hv1);
            s2_lds[tid >> 1] = pk16(sv, sv1);
        }
    }
    if (tid < 8) { sred[tid] = 1.f; yred[tid] = 0.f; }   // ctx_0 = 0
    if (tid < TSTEPS) data_lds[tid] = data[b * TSTEPS + tid];

    const float Wd0 = Wd[0], bd0 = bd[0];
    const float* encB = enc + (size_t)b * T * M;

    // ---- g[tp] = <enc[tp,:], Wd[1:]> ----
    {
        float w0 = Wd[1 + lane * 4], w1 = Wd[2 + lane * 4];
        float w2 = Wd[3 + lane * 4], w3 = Wd[4 + lane * 4];
        for (int i = 0; i < 16; ++i) {
            int tp = wave * 16 + i;
            float4 e4 = *(const float4*)&encB[(size_t)tp * 256 + lane * 4];
            float p = e4.x * w0 + e4.y * w1 + e4.z * w2 + e4.w * w3;
            #pragma unroll
            for (int mm = 32; mm >= 1; mm >>= 1) p += __shfl_xor(p, mm, 64);
            if (lane == 0) g_lds[tp] = p;
        }
    }
    __syncthreads();

    const uint4* h2u4 = (const uint4*)h2_lds;
    const uint4* s2u4 = (const uint4*)s2_lds;

    // ---- prologue: acc_0 = Wr·h_0 (all threads, 1 col each) ----
    {
        const uint4* wc = Wsz + tid;
        float acc = 0.f;
        #pragma unroll 4
        for (int kc = 0; kc < 32; ++kc) {
            uint4 w = wc[kc << 10];
            uint4 h = h2u4[kc];
            acc = dot2(w.x, h.x, acc); acc = dot2(w.y, h.y, acc);
            acc = dot2(w.z, h.z, acc); acc = dot2(w.w, h.w, acc);
        }
        z_lds[(tid >> 8) * 257 + (tid & 255)] = acc;
    }
    __syncthreads();

    if (wave < 8) {
        // ================= G-path (512 threads) =================
        const int gate = tid & 3, uu0 = tid >> 2, uu1 = uu0 + 128;
        const int cz0 = gate * 257 + uu0, cz1 = gate * 257 + uu1;
        const float wk0 = Wk[gate * 256 + uu0], bl0 = bl[gate * 256 + uu0];
        const float wk1 = Wk[gate * 256 + uu1], bl1 = bl[gate * 256 + uu1];
        const int zr = tid >> 8, zc = tid & 255;
        const uint4* wcA = Wsz + tid;
        const uint4* wcB = Wsz + tid + 512;
        uint4 rA[RG], rB[RG];
        #pragma unroll
        for (int kc = 0; kc < RG; ++kc) {
            rA[kc] = wcA[kc << 10]; rB[kc] = wcB[kc << 10];
            KEEP4(rA[kc]); KEEP4(rB[kc]);
        }

        for (int t = 0; t < TSTEPS; ++t) {
            // ---- P1: ys; gates for 2 columns; write h,s,h2,s2 ----
            {
                float4 sa = *(const float4*)&sred[0], sb = *(const float4*)&sred[4];
                float4 yaa = *(const float4*)&yred[0], yab = *(const float4*)&yred[4];
                float S = sa.x + sa.y + sa.z + sa.w + sb.x + sb.y + sb.z + sb.w;
                float Y = yaa.x + yaa.y + yaa.z + yaa.w + yab.x + yab.y + yab.z + yab.w;
                float ys = Y * __builtin_amdgcn_rcpf(S) + data_lds[t] * Wd0 + bd0;
                float zc0 = z_lds[cz0] + ys * wk0 + bl0;
                float zc1 = z_lds[cz1] + ys * wk1 + bl1;
                float nl0 = (gate == 2) ? fast_tanh(zc0) : fast_sigmoid(zc0);
                float nl1 = (gate == 2) ? fast_tanh(zc1) : fast_sigmoid(zc1);
                float a1 = __shfl_xor(nl0, 1, 64);
                float a2 = __shfl_xor(nl0, 2, 64);
                float a3 = __shfl_xor(nl0, 3, 64);
                float b1 = __shfl_xor(nl1, 1, 64);
                float b2 = __shfl_xor(nl1, 2, 64);
                float b3 = __shfl_xor(nl1, 3, 64);
                float hn0 = 0.f, sv0 = 0.f, hn1 = 0.f, sv1 = 0.f;
                if (gate == 0) {            // nl=sig_i a1=sig_f a2=tanh_g a3=sig_o
                    sv0 = a1 * s_lds[uu0] + nl0 * a2;
                    hn0 = a3 * fast_tanh(sv0);
                    sv1 = b1 * s_lds[uu1] + nl1 * b2;
                    hn1 = b3 * fast_tanh(sv1);
                    s_lds[uu0] = sv0; h_lds[uu0] = hn0;
                    s_lds[uu1] = sv1; h_lds[uu1] = hn1;
                }
                float hd0 = __shfl_down(hn0, 4, 64), sd0 = __shfl_down(sv0, 4, 64);
                float hd1 = __shfl_down(hn1, 4, 64), sd1 = __shfl_down(sv1, 4, 64);
                if ((tid & 7) == 0) {
                    h2_lds[uu0 >> 1] = pk16(hn0, hd0); s2_lds[uu0 >> 1] = pk16(sv0, sd0);
                    h2_lds[uu1 >> 1] = pk16(hn1, hd1); s2_lds[uu1 >> 1] = pk16(sv1, sd1);
                }
            }
            __syncthreads();                         // X: h_{t+1} ready

            float a0 = 0.f, a1 = 0.f;
            #pragma unroll
            for (int kc = 0; kc < RG; ++kc) {        // reg-resident: pure VALU
                uint4 h = h2u4[kc];
                a0 = dot2(rA[kc].x, h.x, a0); a0 = dot2(rA[kc].y, h.y, a0);
                a0 = dot2(rA[kc].z, h.z, a0); a0 = dot2(rA[kc].w, h.w, a0);
                a1 = dot2(rB[kc].x, h.x, a1); a1 = dot2(rB[kc].y, h.y, a1);
                a1 = dot2(rB[kc].z, h.z, a1); a1 = dot2(rB[kc].w, h.w, a1);
            }
            #pragma unroll 4
            for (int kc = RG; kc < 32; ++kc) {       // streamed from L2
                uint4 wA = wcA[kc << 10], wB = wcB[kc << 10];
                uint4 h = h2u4[kc];
                a0 = dot2(wA.x, h.x, a0); a0 = dot2(wA.y, h.y, a0);
                a0 = dot2(wA.z, h.z, a0); a0 = dot2(wA.w, h.w, a0);
                a1 = dot2(wB.x, h.x, a1); a1 = dot2(wB.y, h.y, a1);
                a1 = dot2(wB.z, h.z, a1); a1 = dot2(wB.w, h.w, a1);
            }
            z_lds[zr * 257 + zc] = a0;
            z_lds[(2 + zr) * 257 + zc] = a1;
            __syncthreads();                         // Z
        }
    } else {
        // ================= A-path (512 threads) =================
        const int aw  = wave - 8;
        const int aid = tid - 512;
        const int dm  = aid >> 1;                   // D: m-col / E: row
        const int dkh = aid & 1;                    // D: K-half, E: m-half
        const float bwm = bw[dm];
        const uint4* wwp  = Wwsz + (dkh << 13) + dm;        // global stream
        const uint4* wwl  = ww_lds + aid;                   // LDS, wave-linear
        const uint4*  edT = (const uint4*)(&edup[dkh][0]) + (dkh << 4);
        const float4* wvT = (const float4*)(&wv2dup[dkh][0]) + (dkh << 5);
        const uint4* cat4 = dkh ? s2u4 : h2u4;

        // ---- EU row-half into registers (64 regs, pinned) ----
        uint4 eu[16];
        {
            const uint4* eusrc = (const uint4*)(Ue16g + (size_t)b * T * M) + (aid << 4);
            #pragma unroll
            for (int i = 0; i < 16; ++i) { eu[i] = eusrc[i]; KEEP4(eu[i]); }
        }

        for (int t = 0; t < TSTEPS; ++t) {
            __syncthreads();                         // X: h2/s2 ready
            // ---- D: dsc column dm, K-half dkh: 16 LDS chunks + 16 streamed ----
            float a = 0.f;
            #pragma unroll 4
            for (int i = 0; i < 16; ++i) {
                uint4 w = wwl[i << 9];
                uint4 c = cat4[i];
                a = dot2(w.x, c.x, a); a = dot2(w.y, c.y, a);
                a = dot2(w.z, c.z, a); a = dot2(w.w, c.w, a);
            }
            #pragma unroll 4
            for (int i = 16; i < 32; ++i) {
                uint4 w = wwp[i << 8];
                uint4 c = cat4[i];
                a = dot2(w.x, c.x, a); a = dot2(w.y, c.y, a);
                a = dot2(w.z, c.z, a); a = dot2(w.w, c.w, a);
            }
            a += __shfl_xor(a, 1, 64);               // merge K-halves
            float ed = exp2f(1.442695041f * (a + bwm));   // e^{dsc}
            float ed2 = __shfl_xor(ed, 2, 64);            // partner m+1
            if ((aid & 3) == 0) {
                uint u = pk16(ed, ed2);
                edup[0][dm >> 1] = u;
                edup[1][dm >> 1] = u;
            }
            // ---- A-internal sync: all ED written ----
            __threadfence_block();
            if (lane == 0) atomicAdd(&aflag, 1);
            const int tgt = 8 * (t + 1);
            while (*(volatile int*)&aflag < tgt) __builtin_amdgcn_s_sleep(1);
            __threadfence_block();

            // ---- E: per-element rcp form (EU in regs) ----
            __builtin_amdgcn_s_setprio(1);
            float pl = 0.f;                          // Σ 2wv / (q+1), q=(eu·ed)²
            #pragma unroll
            for (int jj = 0; jj < 16; ++jj) {
                uint4 u = eu[jj];
                uint4 d = edT[jj];
                float4 wA = wvT[jj * 2], wB = wvT[jj * 2 + 1];
                uint q0 = pkmulsq(u.x, d.x);
                uint q1 = pkmulsq(u.y, d.y);
                uint q2 = pkmulsq(u.z, d.z);
                uint q3 = pkmulsq(u.w, d.w);
                hf2 g0 = __builtin_bit_cast(hf2, q0);
                hf2 g1 = __builtin_bit_cast(hf2, q1);
                hf2 g2 = __builtin_bit_cast(hf2, q2);
                hf2 g3 = __builtin_bit_cast(hf2, q3);
                pl = fmaf(wA.x, rcp1p((float)g0.x), pl);
                pl = fmaf(wA.y, rcp1p((float)g0.y), pl);
                pl = fmaf(wA.z, rcp1p((float)g1.x), pl);
                pl = fmaf(wA.w, rcp1p((float)g1.y), pl);
                pl = fmaf(wB.x, rcp1p((float)g2.x), pl);
                pl = fmaf(wB.y, rcp1p((float)g2.y), pl);
                pl = fmaf(wB.z, rcp1p((float)g3.x), pl);
                pl = fmaf(wB.w, rcp1p((float)g3.y), pl);
            }
            pl += __shfl_xor(pl, 1, 64);             // merge m-halves
            float ev = exp2f(-1.442695041f * pl);    // softmax const dropped
            if (!dkh) el_lds[dm] = ev;
            float yg = ev * g_lds[dm];
            #pragma unroll
            for (int mm = 2; mm <= 32; mm <<= 1) {
                ev += __shfl_xor(ev, mm, 64);
                yg += __shfl_xor(yg, mm, 64);
            }
            if (lane == 0) { sred[aw] = ev; yred[aw] = yg; }
            __builtin_amdgcn_s_setprio(0);
            __syncthreads();                         // Z
        }
    }

    // ---- epilogue: final ctx from el(254) + fp32 enc, then output head ----
    {
        float S;
        {
            float4 sa = *(const float4*)&sred[0], sb = *(const float4*)&sred[4];
            S = sa.x + sa.y + sa.z + sa.w + sb.x + sb.y + sb.z + sb.w;
        }
        float a0 = 0.f, a1 = 0.f, a2 = 0.f, a3 = 0.f;
        for (int i = 0; i < 16; ++i) {
            int tp = wave * 16 + i;
            float w = el_lds[tp];
            float4 e4 = *(const float4*)&encB[(size_t)tp * 256 + lane * 4];
            a0 += w * e4.x; a1 += w * e4.y; a2 += w * e4.z; a3 += w * e4.w;
        }
        atomicAdd(&ctx_lds[lane * 4 + 0], a0);
        atomicAdd(&ctx_lds[lane * 4 + 1], a1);
        atomicAdd(&ctx_lds[lane * 4 + 2], a2);
        atomicAdd(&ctx_lds[lane * 4 + 3], a3);
        __syncthreads();

        float qp = 0.f;
        if (tid < 256) {
            float ctx = ctx_lds[tid] * __builtin_amdgcn_rcpf(S);
            qp = h_lds[tid] * Wvb[tid] + ctx * Wvb[256 + tid];
        }
        if (wave < 4) {
            #pragma unroll
            for (int mm = 32; mm >= 1; mm >>= 1) qp += __shfl_xor(qp, mm, 64);
            if (lane == 0) ya[wave] = qp;
        }
        __syncthreads();
        if (tid < 256) {
            float qv = ya[0] + ya[1] + ya[2] + ya[3] + bvb[0];
            out[b * 256 + tid] = qv * Wwb[tid] + bwb[tid];
        }
    }
}

extern "C" void kernel_launch(void* const* d_in, const int* in_sizes, int n_in,
                              void* d_out, int out_size, void* d_ws, size_t ws_size,
                              hipStream_t stream) {
    const float* data = (const float*)d_in[0];
    const float* enc  = (const float*)d_in[1];
    const float* h0   = (const float*)d_in[2];
    const float* s0   = (const float*)d_in[3];
    const float* Wd   = (const float*)d_in[4];
    const float* bd   = (const float*)d_in[5];
    const float* Wk   = (const float*)d_in[6];
    const float* Wr   = (const float*)d_in[7];
    const float* bl   = (const float*)d_in[8];
    const float* Ww   = (const float*)d_in[9];
    const float* bw   = (const float*)d_in[10];
    const float* Wu   = (const float*)d_in[11];
    const float* bu   = (const float*)d_in[12];
    const float* Wv   = (const float*)d_in[13];
    const float* bv   = (const float*)d_in[14];
    const float* Wvb  = (const float*)d_in[15];
    const float* bvb  = (const float*)d_in[16];
    const float* Wwb  = (const float*)d_in[17];
    const float* bwb  = (const float*)d_in[18];

    _Float16* Ue16 = (_Float16*)d_ws;                                 // 32 MB
    uint4* Wsz  = (uint4*)((char*)d_ws + (32ull << 20));              // 512 KB
    uint4* Wwsz = (uint4*)((char*)d_ws + (32ull << 20) + (512ull << 10)); // 256 KB
    float* out = (float*)d_out;

    hipLaunchKernelGGL(ue_gemm, dim3((B * T) / 32), dim3(256), 0, stream,
                       enc, Wu, bu, Ue16);
    hipLaunchKernelGGL(wr_cvt, dim3(128), dim3(256), 0, stream, Wr, Wsz);
    hipLaunchKernelGGL(ww_cvt, dim3(64), dim3(256), 0, stream, Ww, Wwsz);
    hipLaunchKernelGGL(decoder_scan, dim3(B), dim3(NT), 0, stream,
                       data, h0, s0, Wd, bd, Wk, bl, bw,
                       Wv, bv, Wvb, bvb, Wwb, bwb,
                       enc, Ue16, Wsz, Wwsz, out);
}

// Round 14
// 2315.437 us; speedup vs baseline: 2.6261x; 1.0308x over previous
//
#include <hip/hip_runtime.h>
#include <hip/hip_bf16.h>

#define B 256
#define T 256
#define M 256
#define P 256
#define TSTEPS 255
#define NT 1024
#define RG 8      // G-resident Wr chunk-pairs (asm-pinned -> AGPR-parked)

typedef unsigned int uint;
typedef _Float16 hf2 __attribute__((ext_vector_type(2)));

#define KEEP4(v) asm volatile("" : "+v"((v).x), "+v"((v).y), "+v"((v).z), "+v"((v).w))

__device__ __forceinline__ float fast_tanh(float x) {
    float e = exp2f(x * 2.885390082f);             // e^(2x)
    return 1.f - 2.f * __builtin_amdgcn_rcpf(e + 1.f);
}
__device__ __forceinline__ float fast_sigmoid(float x) {
    float e = exp2f(-x * 1.442695041f);            // e^(-x)
    return __builtin_amdgcn_rcpf(1.f + e);
}

#if defined(__has_builtin)
#if __has_builtin(__builtin_amdgcn_fdot2)
#define HAVE_FDOT2 1
#endif
#endif

__device__ __forceinline__ float dot2(uint a, uint b, float c) {
#ifdef HAVE_FDOT2
    return __builtin_amdgcn_fdot2(__builtin_bit_cast(hf2, a),
                                  __builtin_bit_cast(hf2, b), c, false);
#else
    hf2 x = __builtin_bit_cast(hf2, a), y = __builtin_bit_cast(hf2, b);
    return c + (float)x.x * (float)y.x + (float)x.y * (float)y.y;
#endif
}

__device__ __forceinline__ uint pk16(float a, float b) {
    return __builtin_bit_cast(uint, __builtin_amdgcn_cvt_pkrtz(a, b));
}

// packed (u*d)^2 + 1 in f16x2 — forced v_pk codegen, +1 fused via pk_fma
__device__ __forceinline__ uint pkmulsq1(uint a, uint b, uint one2) {
    uint p;
    asm("v_pk_mul_f16 %0, %1, %2\n\t"
        "v_pk_fma_f16 %0, %0, %0, %3" : "=&v"(p) : "v"(a), "v"(b), "v"(one2));
    return p;
}

// ---------------- EU = f16(exp(encoder_h @ Wu + bu)) ----------------
__global__ __launch_bounds__(256) void ue_gemm(
    const float* __restrict__ enc, const float* __restrict__ Wu,
    const float* __restrict__ bu, _Float16* __restrict__ Ue16)
{
    __shared__ float At[32][256];
    const int r0 = blockIdx.x * 32;
    const int tid = threadIdx.x;

    #pragma unroll 4
    for (int i = 0; i < 32; ++i)
        At[i][tid] = enc[(size_t)(r0 + i) * 256 + tid];
    __syncthreads();

    float acc[32];
    #pragma unroll
    for (int r = 0; r < 32; ++r) acc[r] = 0.f;

    for (int k = 0; k < 256; k += 4) {
        float w0 = Wu[(size_t)(k + 0) * 256 + tid];
        float w1 = Wu[(size_t)(k + 1) * 256 + tid];
        float w2 = Wu[(size_t)(k + 2) * 256 + tid];
        float w3 = Wu[(size_t)(k + 3) * 256 + tid];
        #pragma unroll
        for (int r = 0; r < 32; ++r) {
            float4 a4 = *(const float4*)&At[r][k];
            acc[r] += a4.x * w0 + a4.y * w1 + a4.z * w2 + a4.w * w3;
        }
    }
    float bub = bu[tid];
    #pragma unroll 4
    for (int r = 0; r < 32; ++r)
        Ue16[(size_t)(r0 + r) * 256 + tid] =
            (_Float16)exp2f(1.442695041f * (acc[r] + bub));   // e^{u}
}

// ---- Wsz[kc*1024+c] = uint4 of f16 pairs of Wr[kc*8+j][c], j=0..7 ----
__global__ __launch_bounds__(256) void wr_cvt(
    const float* __restrict__ Wr, uint4* __restrict__ Wsz)
{
    int i = blockIdx.x * 256 + threadIdx.x;        // 32768
    int kc = i >> 10, c = i & 1023;
    const float* s = Wr + (size_t)kc * 8 * 1024 + c;
    uint4 o;
    o.x = pk16(s[0 * 1024], s[1 * 1024]);
    o.y = pk16(s[2 * 1024], s[3 * 1024]);
    o.z = pk16(s[4 * 1024], s[5 * 1024]);
    o.w = pk16(s[6 * 1024], s[7 * 1024]);
    Wsz[i] = o;
}

// ---- Wwsz[kk*256+m] = uint4 of f16 pairs of Ww[kk*8+j][m], j=0..7 ----
__global__ __launch_bounds__(256) void ww_cvt(
    const float* __restrict__ Ww, uint4* __restrict__ Wwsz)
{
    int i = blockIdx.x * 256 + threadIdx.x;        // 16384
    int kk = i >> 8, m = i & 255;
    const float* s = Ww + (size_t)kk * 8 * 256 + m;
    uint4 o;
    o.x = pk16(s[0 * 256], s[1 * 256]);
    o.y = pk16(s[2 * 256], s[3 * 256]);
    o.z = pk16(s[4 * 256], s[5 * 256]);
    o.w = pk16(s[6 * 256], s[7 * 256]);
    Wwsz[i] = o;
}

// ---------------- main scan: one block (1024 thr) per batch element ----------------
__global__ __launch_bounds__(NT, 4) void decoder_scan(
    const float* __restrict__ data,
    const float* __restrict__ h0,  const float* __restrict__ s0,
    const float* __restrict__ Wd,  const float* __restrict__ bd,
    const float* __restrict__ Wk,  const float* __restrict__ bl,
    const float* __restrict__ bw,
    const float* __restrict__ Wv,  const float* __restrict__ bv,
    const float* __restrict__ Wvb, const float* __restrict__ bvb,
    const float* __restrict__ Wwb, const float* __restrict__ bwb,
    const float* __restrict__ enc,
    const _Float16* __restrict__ Ue16g,
    const uint4* __restrict__ Wsz, const uint4* __restrict__ Wwsz,
    float* __restrict__ out)
{
    const int b    = blockIdx.x;
    const int tid  = threadIdx.x;
    const int lane = tid & 63;
    const int wave = tid >> 6;          // 0..15

    __shared__ __align__(16) uint4 ww_lds[2 * 16 * 256];   // 128 KB, wave-linear layout
    __shared__ float h_lds[P], s_lds[P];
    __shared__ __align__(16) uint hs2[128 + 4 + 128];      // h2 @0, s2 @132
    __shared__ float z_lds[4 * 257];
    __shared__ __align__(16) uint  edup[2][132];           // ED f16 pairs, dup copies
    __shared__ __align__(16) float wv2dup[2][264];         // 2*Wv f32, dup copies
    __shared__ float el_lds[T];
    __shared__ float g_lds[T];
    __shared__ float ctx_lds[M];
    __shared__ __align__(16) float sred[8], yred[8];
    __shared__ float ya[4];
    __shared__ float data_lds[TSTEPS + 1];
    __shared__ int aflag;

    uint* h2_lds = hs2;
    uint* s2_lds = hs2 + 132;

    // ---- stage Ww halves into LDS: ww_lds[(i<<9)+(dm<<1)+dkh] = Wwsz[((dkh*32+i)<<8)+dm]
    {
        #pragma unroll
        for (int k = 0; k < 8; ++k) {
            int l = tid + k * NT;                  // 0..8191
            int i = l >> 9, r = l & 511, dmm = r >> 1, dk = r & 1;
            ww_lds[l] = Wwsz[((dk * 32 + i) << 8) + dmm];
        }
    }
    if (tid == 0) aflag = 0;
    if (tid < 256) {
        float hv = h0[b * 256 + tid], sv = s0[b * 256 + tid];
        h_lds[tid] = hv; s_lds[tid] = sv; ctx_lds[tid] = 0.f;
        float w2 = 2.f * Wv[tid];
        wv2dup[0][tid] = w2; wv2dup[1][tid] = w2;
        float hv1 = __shfl_down(hv, 1, 64);
        float sv1 = __shfl_down(sv, 1, 64);
        if (!(tid & 1)) {
            h2_lds[tid >> 1] = pk16(hv, hv1);
            s2_lds[tid >> 1] = pk16(sv, sv1);
        }
    }
    if (tid < 8) { sred[tid] = 1.f; yred[tid] = 0.f; }   // ctx_0 = 0
    if (tid < TSTEPS) data_lds[tid] = data[b * TSTEPS + tid];

    const float Wd0 = Wd[0], bd0 = bd[0];
    const float* encB = enc + (size_t)b * T * M;

    // ---- g[tp] = <enc[tp,:], Wd[1:]> ----
    {
        float w0 = Wd[1 + lane * 4], w1 = Wd[2 + lane * 4];
        float w2 = Wd[3 + lane * 4], w3 = Wd[4 + lane * 4];
        for (int i = 0; i < 16; ++i) {
            int tp = wave * 16 + i;
            float4 e4 = *(const float4*)&encB[(size_t)tp * 256 + lane * 4];
            float p = e4.x * w0 + e4.y * w1 + e4.z * w2 + e4.w * w3;
            #pragma unroll
            for (int mm = 32; mm >= 1; mm >>= 1) p += __shfl_xor(p, mm, 64);
            if (lane == 0) g_lds[tp] = p;
        }
    }
    __syncthreads();

    const uint4* h2u4 = (const uint4*)h2_lds;
    const uint4* s2u4 = (const uint4*)s2_lds;

    // ---- prologue: acc_0 = Wr·h_0 (all threads, 1 col each) ----
    {
        const uint4* wc = Wsz + tid;
        float acc = 0.f, accb = 0.f;
        #pragma unroll 4
        for (int kc = 0; kc < 32; ++kc) {
            uint4 w = wc[kc << 10];
            uint4 h = h2u4[kc];
            acc  = dot2(w.x, h.x, acc);  acc  = dot2(w.y, h.y, acc);
            accb = dot2(w.z, h.z, accb); accb = dot2(w.w, h.w, accb);
        }
        z_lds[(tid >> 8) * 257 + (tid & 255)] = acc + accb;
    }
    __syncthreads();

    if (wave < 8) {
        // ================= G-path (512 threads) =================
        const int gate = tid & 3, uu0 = tid >> 2, uu1 = uu0 + 128;
        const int cz0 = gate * 257 + uu0, cz1 = gate * 257 + uu1;
        const float wk0 = Wk[gate * 256 + uu0], bl0 = bl[gate * 256 + uu0];
        const float wk1 = Wk[gate * 256 + uu1], bl1 = bl[gate * 256 + uu1];
        const int zr = tid >> 8, zc = tid & 255;
        const uint4* wcA = Wsz + tid;
        const uint4* wcB = Wsz + tid + 512;
        uint4 rA[RG], rB[RG];
        #pragma unroll
        for (int kc = 0; kc < RG; ++kc) {
            rA[kc] = wcA[kc << 10]; rB[kc] = wcB[kc << 10];
            KEEP4(rA[kc]); KEEP4(rB[kc]);
        }

        for (int t = 0; t < TSTEPS; ++t) {
            // ---- P1: ys; gates for 2 columns; write h,s,h2,s2 ----
            {
                float4 sa = *(const float4*)&sred[0], sb = *(const float4*)&sred[4];
                float4 yaa = *(const float4*)&yred[0], yab = *(const float4*)&yred[4];
                float S = sa.x + sa.y + sa.z + sa.w + sb.x + sb.y + sb.z + sb.w;
                float Y = yaa.x + yaa.y + yaa.z + yaa.w + yab.x + yab.y + yab.z + yab.w;
                float ys = Y * __builtin_amdgcn_rcpf(S) + data_lds[t] * Wd0 + bd0;
                float zc0 = z_lds[cz0] + ys * wk0 + bl0;
                float zc1 = z_lds[cz1] + ys * wk1 + bl1;
                float nl0 = (gate == 2) ? fast_tanh(zc0) : fast_sigmoid(zc0);
                float nl1 = (gate == 2) ? fast_tanh(zc1) : fast_sigmoid(zc1);
                float a1 = __shfl_xor(nl0, 1, 64);
                float a2 = __shfl_xor(nl0, 2, 64);
                float a3 = __shfl_xor(nl0, 3, 64);
                float b1 = __shfl_xor(nl1, 1, 64);
                float b2 = __shfl_xor(nl1, 2, 64);
                float b3 = __shfl_xor(nl1, 3, 64);
                float hn0 = 0.f, sv0 = 0.f, hn1 = 0.f, sv1 = 0.f;
                if (gate == 0) {            // nl=sig_i a1=sig_f a2=tanh_g a3=sig_o
                    sv0 = a1 * s_lds[uu0] + nl0 * a2;
                    hn0 = a3 * fast_tanh(sv0);
                    sv1 = b1 * s_lds[uu1] + nl1 * b2;
                    hn1 = b3 * fast_tanh(sv1);
                    s_lds[uu0] = sv0; h_lds[uu0] = hn0;
                    s_lds[uu1] = sv1; h_lds[uu1] = hn1;
                }
                float hd0 = __shfl_down(hn0, 4, 64), sd0 = __shfl_down(sv0, 4, 64);
                float hd1 = __shfl_down(hn1, 4, 64), sd1 = __shfl_down(sv1, 4, 64);
                if ((tid & 7) == 0) {
                    h2_lds[uu0 >> 1] = pk16(hn0, hd0); s2_lds[uu0 >> 1] = pk16(sv0, sd0);
                    h2_lds[uu1 >> 1] = pk16(hn1, hd1); s2_lds[uu1 >> 1] = pk16(sv1, sd1);
                }
            }
            __syncthreads();                         // X: h_{t+1} ready

            float a0 = 0.f, a0b = 0.f, a1 = 0.f, a1b = 0.f;
            #pragma unroll
            for (int kc = 0; kc < RG; ++kc) {        // reg-resident: pure VALU
                uint4 h = h2u4[kc];
                a0  = dot2(rA[kc].x, h.x, a0);  a0  = dot2(rA[kc].y, h.y, a0);
                a0b = dot2(rA[kc].z, h.z, a0b); a0b = dot2(rA[kc].w, h.w, a0b);
                a1  = dot2(rB[kc].x, h.x, a1);  a1  = dot2(rB[kc].y, h.y, a1);
                a1b = dot2(rB[kc].z, h.z, a1b); a1b = dot2(rB[kc].w, h.w, a1b);
            }
            #pragma unroll 4
            for (int kc = RG; kc < 32; ++kc) {       // streamed from L2
                uint4 wA = wcA[kc << 10], wB = wcB[kc << 10];
                uint4 h = h2u4[kc];
                a0  = dot2(wA.x, h.x, a0);  a0  = dot2(wA.y, h.y, a0);
                a0b = dot2(wA.z, h.z, a0b); a0b = dot2(wA.w, h.w, a0b);
                a1  = dot2(wB.x, h.x, a1);  a1  = dot2(wB.y, h.y, a1);
                a1b = dot2(wB.z, h.z, a1b); a1b = dot2(wB.w, h.w, a1b);
            }
            z_lds[zr * 257 + zc] = a0 + a0b;
            z_lds[(2 + zr) * 257 + zc] = a1 + a1b;
            __syncthreads();                         // Z
        }
    } else {
        // ================= A-path (512 threads) =================
        const int aw  = wave - 8;
        const int aid = tid - 512;
        const int dm  = aid >> 1;                   // D: m-col / E: row
        const int dkh = aid & 1;                    // D: K-half, E: m-half
        const float bwm = bw[dm];
        const uint4* wwp  = Wwsz + (dkh << 13) + dm;        // global stream
        const uint4* wwl  = ww_lds + aid;                   // LDS, wave-linear
        const uint4*  edT = (const uint4*)(&edup[dkh][0]) + (dkh << 4);
        const float4* wvT = (const float4*)(&wv2dup[dkh][0]) + (dkh << 5);
        const uint4* cat4 = dkh ? s2u4 : h2u4;
        const uint one2 = 0x3C003C00u;              // f16x2 {1.0, 1.0}

        // ---- EU row-half into registers (64 regs, pinned) ----
        uint4 eu[16];
        {
            const uint4* eusrc = (const uint4*)(Ue16g + (size_t)b * T * M) + (aid << 4);
            #pragma unroll
            for (int i = 0; i < 16; ++i) { eu[i] = eusrc[i]; KEEP4(eu[i]); }
        }

        for (int t = 0; t < TSTEPS; ++t) {
            __syncthreads();                         // X: h2/s2 ready
            // ---- D: dsc column dm, K-half dkh: 16 LDS chunks + 16 streamed ----
            float a = 0.f, ab = 0.f;
            #pragma unroll 4
            for (int i = 0; i < 16; ++i) {
                uint4 w = wwl[i << 9];
                uint4 c = cat4[i];
                a  = dot2(w.x, c.x, a);  a  = dot2(w.y, c.y, a);
                ab = dot2(w.z, c.z, ab); ab = dot2(w.w, c.w, ab);
            }
            #pragma unroll 4
            for (int i = 16; i < 32; ++i) {
                uint4 w = wwp[i << 8];
                uint4 c = cat4[i];
                a  = dot2(w.x, c.x, a);  a  = dot2(w.y, c.y, a);
                ab = dot2(w.z, c.z, ab); ab = dot2(w.w, c.w, ab);
            }
            a += ab;
            a += __shfl_xor(a, 1, 64);               // merge K-halves
            float ed = exp2f(1.442695041f * (a + bwm));   // e^{dsc}
            float ed2 = __shfl_xor(ed, 2, 64);            // partner m+1
            if ((aid & 3) == 0) {
                uint u = pk16(ed, ed2);
                edup[0][dm >> 1] = u;
                edup[1][dm >> 1] = u;
            }
            // ---- A-internal sync: all ED written ----
            __threadfence_block();
            if (lane == 0) atomicAdd(&aflag, 1);
            const int tgt = 8 * (t + 1);
            while (*(volatile int*)&aflag < tgt) __builtin_amdgcn_s_sleep(1);
            __threadfence_block();

            // ---- E: per-element rcp form (EU in regs), fused +1, 2 accs ----
            __builtin_amdgcn_s_setprio(1);
            float pl0 = 0.f, pl1 = 0.f;              // Σ 2wv / ((eu·ed)² + 1)
            #pragma unroll
            for (int jj = 0; jj < 16; ++jj) {
                uint4 u = eu[jj];
                uint4 d = edT[jj];
                float4 wA = wvT[jj * 2], wB = wvT[jj * 2 + 1];
                uint q0 = pkmulsq1(u.x, d.x, one2);
                uint q1 = pkmulsq1(u.y, d.y, one2);
                uint q2 = pkmulsq1(u.z, d.z, one2);
                uint q3 = pkmulsq1(u.w, d.w, one2);
                hf2 g0 = __builtin_bit_cast(hf2, q0);
                hf2 g1 = __builtin_bit_cast(hf2, q1);
                hf2 g2 = __builtin_bit_cast(hf2, q2);
                hf2 g3 = __builtin_bit_cast(hf2, q3);
                pl0 = fmaf(wA.x, __builtin_amdgcn_rcpf((float)g0.x), pl0);
                pl1 = fmaf(wA.y, __builtin_amdgcn_rcpf((float)g0.y), pl1);
                pl0 = fmaf(wA.z, __builtin_amdgcn_rcpf((float)g1.x), pl0);
                pl1 = fmaf(wA.w, __builtin_amdgcn_rcpf((float)g1.y), pl1);
                pl0 = fmaf(wB.x, __builtin_amdgcn_rcpf((float)g2.x), pl0);
                pl1 = fmaf(wB.y, __builtin_amdgcn_rcpf((float)g2.y), pl1);
                pl0 = fmaf(wB.z, __builtin_amdgcn_rcpf((float)g3.x), pl0);
                pl1 = fmaf(wB.w, __builtin_amdgcn_rcpf((float)g3.y), pl1);
            }
            float pl = pl0 + pl1;
            pl += __shfl_xor(pl, 1, 64);             // merge m-halves
            float ev = exp2f(-1.442695041f * pl);    // softmax const dropped
            if (!dkh) el_lds[dm] = ev;
            float yg = ev * g_lds[dm];
            #pragma unroll
            for (int mm = 2; mm <= 32; mm <<= 1) {
                ev += __shfl_xor(ev, mm, 64);
                yg += __shfl_xor(yg, mm, 64);
            }
            if (lane == 0) { sred[aw] = ev; yred[aw] = yg; }
            __builtin_amdgcn_s_setprio(0);
            __syncthreads();                         // Z
        }
    }

    // ---- epilogue: final ctx from el(254) + fp32 enc, then output head ----
    {
        float S;
        {
            float4 sa = *(const float4*)&sred[0], sb = *(const float4*)&sred[4];
            S = sa.x + sa.y + sa.z + sa.w + sb.x + sb.y + sb.z + sb.w;
        }
        float a0 = 0.f, a1 = 0.f, a2 = 0.f, a3 = 0.f;
        for (int i = 0; i < 16; ++i) {
            int tp = wave * 16 + i;
            float w = el_lds[tp];
            float4 e4 = *(const float4*)&encB[(size_t)tp * 256 + lane * 4];
            a0 += w * e4.x; a1 += w * e4.y; a2 += w * e4.z; a3 += w * e4.w;
        }
        atomicAdd(&ctx_lds[lane * 4 + 0], a0);
        atomicAdd(&ctx_lds[lane * 4 + 1], a1);
        atomicAdd(&ctx_lds[lane * 4 + 2], a2);
        atomicAdd(&ctx_lds[lane * 4 + 3], a3);
        __syncthreads();

        float qp = 0.f;
        if (tid < 256) {
            float ctx = ctx_lds[tid] * __builtin_amdgcn_rcpf(S);
            qp = h_lds[tid] * Wvb[tid] + ctx * Wvb[256 + tid];
        }
        if (wave < 4) {
            #pragma unroll
            for (int mm = 32; mm >= 1; mm >>= 1) qp += __shfl_xor(qp, mm, 64);
            if (lane == 0) ya[wave] = qp;
        }
        __syncthreads();
        if (tid < 256) {
            float qv = ya[0] + ya[1] + ya[2] + ya[3] + bvb[0];
            out[b * 256 + tid] = qv * Wwb[tid] + bwb[tid];
        }
    }
}

extern "C" void kernel_launch(void* const* d_in, const int* in_sizes, int n_in,
                              void* d_out, int out_size, void* d_ws, size_t ws_size,
                              hipStream_t stream) {
    const float* data = (const float*)d_in[0];
    const float* enc  = (const float*)d_in[1];
    const float* h0   = (const float*)d_in[2];
    const float* s0   = (const float*)d_in[3];
    const float* Wd   = (const float*)d_in[4];
    const float* bd   = (const float*)d_in[5];
    const float* Wk   = (const float*)d_in[6];
    const float* Wr   = (const float*)d_in[7];
    const float* bl   = (const float*)d_in[8];
    const float* Ww   = (const float*)d_in[9];
    const float* bw   = (const float*)d_in[10];
    const float* Wu   = (const float*)d_in[11];
    const float* bu   = (const float*)d_in[12];
    const float* Wv   = (const float*)d_in[13];
    const float* bv   = (const float*)d_in[14];
    const float* Wvb  = (const float*)d_in[15];
    const float* bvb  = (const float*)d_in[16];
    const float* Wwb  = (const float*)d_in[17];
    const float* bwb  = (const float*)d_in[18];

    _Float16* Ue16 = (_Float16*)d_ws;                                 // 32 MB
    uint4* Wsz  = (uint4*)((char*)d_ws + (32ull << 20));              // 512 KB
    uint4* Wwsz = (uint4*)((char*)d_ws + (32ull << 20) + (512ull << 10)); // 256 KB
    float* out = (float*)d_out;

    hipLaunchKernelGGL(ue_gemm, dim3((B * T) / 32), dim3(256), 0, stream,
                       enc, Wu, bu, Ue16);
    hipLaunchKernelGGL(wr_cvt, dim3(128), dim3(256), 0, stream, Wr, Wsz);
    hipLaunchKernelGGL(ww_cvt, dim3(64), dim3(256), 0, stream, Ww, Wwsz);
    hipLaunchKernelGGL(decoder_scan, dim3(B), dim3(NT), 0, stream,
                       data, h0, s0, Wd, bd, Wk, bl, bw,
                       Wv, bv, Wvb, bvb, Wwb, bwb,
                       enc, Ue16, Wsz, Wwsz, out);
}